// Round 1
// 256.593 us; speedup vs baseline: 1.0266x; 1.0266x over previous
//
#include <hip/hip_runtime.h>
#include <math.h>

#define B 4
#define C 64
#define H 256
#define W 256
#define CMID 16
#define CIN 73        // 64 + 9
#define HW (H*W)
#define NW (CIN*9*CMID)   // 10512 conv1 weights
#define XS_STRIDE 260     // LDS row stride: [0]=left halo, [1..256]=x, [257]=right halo

// ---------------------------------------------------------------------------
// w1 (CMID, CIN, 3, 3) -> wt[(ci*9+k)*CMID + co]
// ---------------------------------------------------------------------------
__global__ void transpose_w1_kernel(const float* __restrict__ w1, float* __restrict__ wt) {
    int tid = blockIdx.x * blockDim.x + threadIdx.x;
    if (tid >= NW) return;
    int co = tid & (CMID - 1);
    int rest = tid >> 4;          // ci*9 + k
    int ci = rest / 9;
    int k = rest - ci * 9;
    wt[tid] = w1[(co * CIN + ci) * 9 + k];
}

// ---------------------------------------------------------------------------
// 1-px/thread row-block decode (sim + conv1):
// grid = B*H = 1024 blocks -> 4 blocks/CU (4 waves/SIMD). Block = (b, row y).
// 256 threads, px = tid. Stage rows y-1..y+1 per channel, 4 channels/barrier.
// Staging writes are lane-consecutive (conflict-free); patch reads likewise.
// ---------------------------------------------------------------------------

// 3x3 patch from one channel plane. base = &xs[ch][tid].
// stored layout xs[row][1+col] = x[col]; base[j*STRIDE + i] = x[px-1+i].
__device__ __forceinline__ void read_patch9(const float* __restrict__ base, float v[9]) {
#pragma unroll
    for (int r = 0; r < 3; ++r) {
        v[r * 3 + 0] = base[r * XS_STRIDE + 0];
        v[r * 3 + 1] = base[r * XS_STRIDE + 1];
        v[r * 3 + 2] = base[r * XS_STRIDE + 2];
    }
}

__device__ __forceinline__ void zero_halo48(float* __restrict__ xs0, int tid) {
    // xs layout [2][4][3*XS_STRIDE]: zero slots {0,257} of every row once.
    if (tid < 48) {
        int e = tid & 1;
        int r = (tid >> 1) % 3;
        int q = (tid >> 1) / 3;      // 0..7 = buf*4 + ch
        xs0[q * (3 * XS_STRIDE) + r * XS_STRIDE + (e ? 257 : 0)] = 0.f;
    }
}

// ---------------------------------------------------------------------------
// Local cosine similarity. 1 px/thread, 4 ch per barrier, double-buffered.
// ---------------------------------------------------------------------------
__global__ __launch_bounds__(256) void sim_kernel(const float* __restrict__ x,
                                                  float* __restrict__ sim) {
    __shared__ float xs[2][4][3 * XS_STRIDE];   // 24960 B

    int bid = blockIdx.x;
    int b = bid >> 8;
    int y = bid & 255;
    int tid = threadIdx.x;

    const float* xb = x + (size_t)b * C * HW;

    bool rv[3];
    long off[3];
#pragma unroll
    for (int j = 0; j < 3; ++j) {
        int grow = y - 1 + j;
        rv[j] = (grow >= 0) && (grow < H);
        off[j] = (long)grow * W + tid;
    }

    zero_halo48(&xs[0][0][0], tid);

    float dot[9], nsq[9];
    float csq = 0.f;
#pragma unroll
    for (int i = 0; i < 9; ++i) { dot[i] = nsq[i] = 0.f; }

    // prefetch group cc=0
    float p[12];
#pragma unroll
    for (int k = 0; k < 4; ++k)
#pragma unroll
        for (int j = 0; j < 3; ++j)
            p[k * 3 + j] = rv[j] ? xb[(size_t)k * HW + off[j]] : 0.f;

    int cur = 0;
#pragma unroll 1
    for (int cc = 0; cc < C; cc += 4) {
#pragma unroll
        for (int k = 0; k < 4; ++k)
#pragma unroll
            for (int j = 0; j < 3; ++j)
                xs[cur][k][j * XS_STRIDE + 1 + tid] = p[k * 3 + j];
        __syncthreads();

        if (cc + 4 < C) {
#pragma unroll
            for (int k = 0; k < 4; ++k)
#pragma unroll
                for (int j = 0; j < 3; ++j)
                    p[k * 3 + j] = rv[j] ? xb[(size_t)(cc + 4 + k) * HW + off[j]] : 0.f;
        }

#pragma unroll
        for (int k = 0; k < 4; ++k) {
            float v[9];
            read_patch9(&xs[cur][k][tid], v);
            float cv = v[4];
            csq = fmaf(cv, cv, csq);
#pragma unroll
            for (int kk = 0; kk < 9; ++kk) {
                if (kk == 4) continue;
                dot[kk] = fmaf(cv, v[kk], dot[kk]);
                nsq[kk] = fmaf(v[kk], v[kk], nsq[kk]);
            }
        }
        cur ^= 1;
    }

    dot[4] = csq;
    nsq[4] = csq;
    float cn = sqrtf(csq) + 1e-8f;
    float* so = sim + (size_t)b * 9 * HW + (size_t)y * W + tid;
#pragma unroll
    for (int kk = 0; kk < 9; ++kk)
        so[(size_t)kk * HW] = dot[kk] / (cn * (sqrtf(nsq[kk]) + 1e-8f));
}

// ---------------------------------------------------------------------------
// Conv1 (73->16) + leaky. 1 px/thread, 4 ch per barrier, double-buffered.
// Weights read at wave-uniform addresses -> scalar s_load pipe.
// ---------------------------------------------------------------------------
__device__ __forceinline__ void conv1_chan1(const float* __restrict__ base,
                                            const float* __restrict__ wp,  // uniform!
                                            float acc[CMID]) {
    float v[9];
    read_patch9(base, v);
#pragma unroll
    for (int k = 0; k < 9; ++k) {
        const float* w = wp + k * CMID;
        float a = v[k];
#pragma unroll
        for (int co = 0; co < CMID; ++co)
            acc[co] = fmaf(a, w[co], acc[co]);
    }
}

__global__ __launch_bounds__(256) void conv1_kernel(const float* __restrict__ x,
                                                    const float* __restrict__ sim,
                                                    const float* __restrict__ wt,
                                                    const float* __restrict__ b1,
                                                    float* __restrict__ h) {
    __shared__ float xs[2][4][3 * XS_STRIDE];   // 24960 B

    int bid = blockIdx.x;
    int b = bid >> 8;
    int y = bid & 255;
    int tid = threadIdx.x;

    const float* gx = x + (size_t)b * C * HW;
    const float* gs = sim + (size_t)b * 9 * HW;

    bool rv[3];
    long off[3];
#pragma unroll
    for (int j = 0; j < 3; ++j) {
        int grow = y - 1 + j;
        rv[j] = (grow >= 0) && (grow < H);
        off[j] = (long)grow * W + tid;
    }

    zero_halo48(&xs[0][0][0], tid);

    float acc[CMID];
#pragma unroll
    for (int co = 0; co < CMID; ++co) acc[co] = b1[co];

    // prefetch group cc=0 (all ci < C here)
    float p[12];
#pragma unroll
    for (int k = 0; k < 4; ++k)
#pragma unroll
        for (int j = 0; j < 3; ++j)
            p[k * 3 + j] = rv[j] ? gx[(size_t)k * HW + off[j]] : 0.f;

    int cur = 0;
#pragma unroll 1
    for (int cc = 0; cc < 72; cc += 4) {
#pragma unroll
        for (int k = 0; k < 4; ++k)
#pragma unroll
            for (int j = 0; j < 3; ++j)
                xs[cur][k][j * XS_STRIDE + 1 + tid] = p[k * 3 + j];
        __syncthreads();

        // prefetch group cc+4 (guard ci < CIN; uniform branches)
#pragma unroll
        for (int k = 0; k < 4; ++k) {
            int ci = cc + 4 + k;
            if (ci < CIN) {
                const float* cb = (ci < C) ? (gx + (size_t)ci * HW)
                                           : (gs + (size_t)(ci - C) * HW);
#pragma unroll
                for (int j = 0; j < 3; ++j)
                    p[k * 3 + j] = rv[j] ? cb[off[j]] : 0.f;
            }
        }

        conv1_chan1(&xs[cur][0][tid], wt + (size_t)cc * 144, acc);
        conv1_chan1(&xs[cur][1][tid], wt + (size_t)(cc + 1) * 144, acc);
        conv1_chan1(&xs[cur][2][tid], wt + (size_t)(cc + 2) * 144, acc);
        conv1_chan1(&xs[cur][3][tid], wt + (size_t)(cc + 3) * 144, acc);
        cur ^= 1;
    }

    // tail channel ci = 72 (prefetched as k=0 of the cc=68 iteration)
#pragma unroll
    for (int j = 0; j < 3; ++j)
        xs[cur][0][j * XS_STRIDE + 1 + tid] = p[j];
    __syncthreads();
    conv1_chan1(&xs[cur][0][tid], wt + (size_t)72 * 144, acc);

    float* ho = h + (size_t)b * CMID * HW + (size_t)y * W + tid;
#pragma unroll
    for (int co = 0; co < CMID; ++co) {
        float v0 = acc[co];
        v0 = v0 >= 0.f ? v0 : 0.2f * v0;
        ho[(size_t)co * HW] = v0;
    }
}

// ---------------------------------------------------------------------------
// Strip helpers for offset kernel (unchanged 2-px/thread structure).
// ---------------------------------------------------------------------------
__device__ __forceinline__ void read_patch_lds(const float* __restrict__ xsbuf,
                                               int rl, int px, float v[3][4]) {
    const float* pb = xsbuf + rl * XS_STRIDE + px;
#pragma unroll
    for (int r = 0; r < 3; ++r) {
        float2 p0 = *(const float2*)(pb + r * XS_STRIDE);
        float2 p1 = *(const float2*)(pb + r * XS_STRIDE + 2);
        v[r][0] = p0.x; v[r][1] = p0.y; v[r][2] = p1.x; v[r][3] = p1.y;
    }
}

// ---------------------------------------------------------------------------
// Conv2 (16->2) + tanh -> clamped sample coords. (unchanged)
// ---------------------------------------------------------------------------
__global__ __launch_bounds__(256) void offset_kernel(const float* __restrict__ h,
                                                     const float* __restrict__ w2,
                                                     const float* __restrict__ b2,
                                                     float2* __restrict__ off_buf) {
    __shared__ float lw2[CMID * 9 * 2];
    __shared__ float xs[2][4 * XS_STRIDE];

    int tid = threadIdx.x;
    for (int i = tid; i < CMID * 9 * 2; i += 256) {
        int co = i & 1;
        int rest = i >> 1;
        int ci = rest / 9;
        int kk = rest - ci * 9;
        lw2[i] = w2[(co * CMID + ci) * 9 + kk];
    }

    int bid = blockIdx.x;
    int b  = bid >> 7;
    int y0 = (bid & 127) << 1;
    int srow = tid >> 6;
    int sx4  = (tid & 63) << 2;
    int rl = tid >> 7;
    int px = (tid & 127) << 1;
    int y  = y0 + rl;

    int grow = y0 - 1 + srow;
    bool gvalid = (grow >= 0) && (grow < H);
    const float* gh = h + (size_t)b * CMID * HW + (size_t)grow * W + sx4;

    if (tid < 16) {
        int bu = tid >> 3, r = (tid >> 1) & 3, e = (tid & 1) ? 257 : 0;
        xs[bu][r * XS_STRIDE + e] = 0.f;
    }

    float s0x = b2[0], s0y = b2[1], s1x = b2[0], s1y = b2[1];

    float4 r4 = make_float4(0.f, 0.f, 0.f, 0.f);
    if (gvalid) r4 = *(const float4*)gh;

    int cur = 0;
#pragma unroll 1
    for (int ci = 0; ci < CMID; ++ci) {
        float* dst = &xs[cur][srow * XS_STRIDE + 1 + sx4];
        dst[0] = r4.x; dst[1] = r4.y; dst[2] = r4.z; dst[3] = r4.w;
        __syncthreads();
        if (ci + 1 < CMID) {
            r4 = make_float4(0.f, 0.f, 0.f, 0.f);
            if (gvalid) r4 = *(const float4*)(gh + (size_t)(ci + 1) * HW);
        }
        float v[3][4];
        read_patch_lds(xs[cur], rl, px, v);
#pragma unroll
        for (int kr = 0; kr < 3; ++kr)
#pragma unroll
            for (int kc = 0; kc < 3; ++kc) {
                float2 wv = *(const float2*)(lw2 + (ci * 9 + kr * 3 + kc) * 2);
                s0x = fmaf(v[kr][kc],     wv.x, s0x);
                s0y = fmaf(v[kr][kc],     wv.y, s0y);
                s1x = fmaf(v[kr][kc + 1], wv.x, s1x);
                s1y = fmaf(v[kr][kc + 1], wv.y, s1y);
            }
        cur ^= 1;
    }

    float ix0 = (float)px       + 0.1f * tanhf(s0x) * (0.5f * (float)(W - 1));
    float iy0 = (float)y        + 0.1f * tanhf(s0y) * (0.5f * (float)(H - 1));
    float ix1 = (float)(px + 1) + 0.1f * tanhf(s1x) * (0.5f * (float)(W - 1));
    float iy1 = (float)y        + 0.1f * tanhf(s1y) * (0.5f * (float)(H - 1));
    ix0 = fminf(fmaxf(ix0, 0.f), (float)(W - 1));
    iy0 = fminf(fmaxf(iy0, 0.f), (float)(H - 1));
    ix1 = fminf(fmaxf(ix1, 0.f), (float)(W - 1));
    iy1 = fminf(fmaxf(iy1, 0.f), (float)(H - 1));

    float4* op = (float4*)(off_buf + (size_t)b * HW + (size_t)y * W + px);
    *op = make_float4(ix0, iy0, ix1, iy1);
}

// ---------------------------------------------------------------------------
// Bilinear border sample via LDS row cache. (unchanged)
// ---------------------------------------------------------------------------
#define SROWS 35
__global__ __launch_bounds__(256) void sample_kernel(const float* __restrict__ x,
                                                     const float2* __restrict__ off_buf,
                                                     float* __restrict__ out) {
    __shared__ float xs[SROWS * 256];    // 35840 B

    int bid = blockIdx.x;                        // 0..127 tiles
    int sb = (bid & 7) * 16 + (bid >> 3);        // XCD-contiguous 16-tile bands
    int b  = sb >> 5;
    int ty = sb & 31;
    int cg = blockIdx.y;                         // 0..15 channel groups (4 ch)
    int tid = threadIdx.x;                       // column

    int ybase = ty << 3;
    int lo = ybase - 13;

    int a00[8], a01[8], a10[8], a11[8];
    float wx[8], wy[8];
    const float2* ob2 = off_buf + (size_t)b * HW + (size_t)ybase * W + tid;
#pragma unroll
    for (int r = 0; r < 8; ++r) {
        float2 o = ob2[r * W];
        float xf = floorf(o.x), yf = floorf(o.y);
        wx[r] = o.x - xf; wy[r] = o.y - yf;
        int x0 = (int)xf, yy0 = (int)yf;
        int x1 = min(x0 + 1, W - 1), yy1 = min(yy0 + 1, H - 1);
        int r0 = (yy0 - lo) << 8, r1 = (yy1 - lo) << 8;
        a00[r] = r0 + x0; a01[r] = r0 + x1;
        a10[r] = r1 + x0; a11[r] = r1 + x1;
    }

    const float* xb = x + ((size_t)b * C + cg * 4) * HW;
    float* outb = out + ((size_t)b * C + cg * 4) * HW + (size_t)ybase * W + tid;

#pragma unroll 1
    for (int c = 0; c < 4; ++c) {
        __syncthreads();
        const float* src = xb + (size_t)c * HW;
        for (int j = tid; j < SROWS * 64; j += 256) {
            int row = j >> 6, x4 = (j & 63) << 2;
            int grw = min(max(lo + row, 0), H - 1);
            *(float4*)&xs[(row << 8) + x4] = *(const float4*)(src + (size_t)grw * W + x4);
        }
        __syncthreads();
        float* oc = outb + (size_t)c * HW;
#pragma unroll
        for (int r = 0; r < 8; ++r) {
            float v00 = xs[a00[r]], v01 = xs[a01[r]];
            float v10 = xs[a10[r]], v11 = xs[a11[r]];
            float top = fmaf(wx[r], v01 - v00, v00);
            float bot = fmaf(wx[r], v11 - v10, v10);
            oc[r * W] = fmaf(wy[r], bot - top, top);
        }
    }
}

// ---------------------------------------------------------------------------
extern "C" void kernel_launch(void* const* d_in, const int* in_sizes, int n_in,
                              void* d_out, int out_size, void* d_ws, size_t ws_size,
                              hipStream_t stream) {
    const float* x  = (const float*)d_in[0];
    const float* w1 = (const float*)d_in[1];
    const float* b1 = (const float*)d_in[2];
    const float* w2 = (const float*)d_in[3];
    const float* b2 = (const float*)d_in[4];
    float* out = (float*)d_out;

    float* ws  = (float*)d_ws;
    float* wt  = ws;                                         // 16384 floats
    float* sim = ws + 16384;                                 // B*9*HW
    float* h   = sim + (size_t)B * 9 * HW;                   // B*16*HW
    float2* off_buf = (float2*)(h + (size_t)B * CMID * HW);  // B*HW float2

    transpose_w1_kernel<<<(NW + 255) / 256, 256, 0, stream>>>(w1, wt);

    sim_kernel<<<B * H, 256, 0, stream>>>(x, sim);
    conv1_kernel<<<B * H, 256, 0, stream>>>(x, sim, wt, b1, h);
    offset_kernel<<<512, 256, 0, stream>>>(h, w2, b2, off_buf);
    sample_kernel<<<dim3(128, 16), 256, 0, stream>>>(x, off_buf, out);
}